// Round 5
// baseline (1114.949 us; speedup 1.0000x reference)
//
#include <hip/hip_runtime.h>

#define B_SZ 4096
#define D_SZ 1024
#define K_SZ 32
#define NT   32          // K-depth steps of 32

typedef _Float16 h16x8 __attribute__((ext_vector_type(8)));
typedef float f32x16 __attribute__((ext_vector_type(16)));
typedef float f32x4 __attribute__((ext_vector_type(4)));
typedef float f32x2 __attribute__((ext_vector_type(2)));
typedef unsigned int u32x2 __attribute__((ext_vector_type(2)));
typedef unsigned int u32x4 __attribute__((ext_vector_type(4)));
typedef unsigned short u16x4 __attribute__((ext_vector_type(4)));

// async global->LDS, 16B per lane (wave-uniform LDS base + lane*16)
#define GLOAD16(gp, sp) __builtin_amdgcn_global_load_lds( \
    (const __attribute__((address_space(1))) void*)(gp),  \
    (__attribute__((address_space(3))) void*)(sp), 16, 0, 0)

// fp32 -> fp16 hi + fp16 lo*2^11 (lo scaled to stay normal)
__device__ __forceinline__ void split1(float x, _Float16& h, _Float16& l) {
    h = (_Float16)x;
    l = (_Float16)((x - (float)h) * 2048.0f);
}

// ---------------- prepass: W[k][d][e] f32 -> Wt_h/Wt_l[k][e][d] fp16 ----------------
__global__ __launch_bounds__(256)
void ntl_prep_w(const float* __restrict__ W,
                _Float16* __restrict__ Wh, _Float16* __restrict__ Wl) {
    __shared__ float tile[64 * 69];
    const int bid = blockIdx.x;
    const int k  = bid >> 8;
    const int d0 = ((bid >> 4) & 15) << 6;
    const int e0 = (bid & 15) << 6;
    const int t  = threadIdx.x;
    const int r  = t >> 4;
    const int c4 = (t & 15) << 2;

    const float* src = W + ((size_t)k * D_SZ + d0) * D_SZ + e0;
    #pragma unroll
    for (int p = 0; p < 4; ++p) {
        f32x4 v = *(const f32x4*)(src + (size_t)(p * 16 + r) * D_SZ + c4);
        float* dst = &tile[(p * 16 + r) * 69 + c4];
        dst[0] = v[0]; dst[1] = v[1]; dst[2] = v[2]; dst[3] = v[3];
    }
    __syncthreads();
    #pragma unroll
    for (int p = 0; p < 4; ++p) {
        const int e = p * 16 + r;
        u16x4 hh, ll;
        #pragma unroll
        for (int q = 0; q < 4; ++q) {
            float v = tile[(c4 + q) * 69 + e];
            _Float16 h, l;
            split1(v, h, l);
            hh[q] = __builtin_bit_cast(unsigned short, h);
            ll[q] = __builtin_bit_cast(unsigned short, l);
        }
        const size_t o = ((size_t)k * D_SZ + e0 + e) * D_SZ + d0 + c4;
        *(u16x4*)(Wh + o) = hh;
        *(u16x4*)(Wl + o) = ll;
    }
}

// ---------------- prepass: e1 f32 -> e1_h/e1_l fp16 ----------------
__global__ __launch_bounds__(256)
void ntl_prep_e(const float* __restrict__ e1,
                _Float16* __restrict__ eh, _Float16* __restrict__ el) {
    const size_t i = ((size_t)blockIdx.x * 256 + threadIdx.x) * 4;
    f32x4 v = *(const f32x4*)(e1 + i);
    u16x4 hh, ll;
    #pragma unroll
    for (int q = 0; q < 4; ++q) {
        _Float16 h, l;
        split1(v[q], h, l);
        hh[q] = __builtin_bit_cast(unsigned short, h);
        ll[q] = __builtin_bit_cast(unsigned short, l);
    }
    *(u16x4*)(eh + i) = hh;
    *(u16x4*)(el + i) = ll;
}

// ---------------- main bilinear: 256x128 tile, BK=32, 8 waves, 2-phase dbuf ----------
// LDS 96KB = 2 bufs x 48KB. Buf layout: Ah [0,16K) Al [16K,32K) Bh [32K,40K) Bl [40K,48K).
// A/B tiles packed 2 rows per 128B line; 16B slot s at line L holds
// (row = 2L + pr, kgran = pk) with (pr<<2|pk) = s ^ (L&7)  [8-slot XOR swizzle].
// ALL staging via global_load_lds (linear dest, pre-swizzled global source, rule #21);
// zero ds_writes in the main loop. One __syncthreads per iter (vmcnt0+lgkm0+barrier):
// next-tile loads are issued BEFORE compute, so the drain has a full MFMA phase of slack.
__global__ __launch_bounds__(512, 2)
void ntl_bilinear5(const _Float16* __restrict__ eh, const _Float16* __restrict__ el,
                   const _Float16* __restrict__ Wh, const _Float16* __restrict__ Wl,
                   const float* __restrict__ e2, float* __restrict__ out) {
    __shared__ __align__(16) char lds[98304];

    const int bid   = blockIdx.x;
    const int xcd   = bid & 7;
    const int idx   = bid >> 3;         // 0..511 per XCD
    const int e_t   = idx & 7;          // 8 e-tiles
    const int b_sub = (idx >> 3) & 1;   // 2 b-tiles per XCD
    const int k     = idx >> 4;         // 0..31, slowest (W[k] stays hot)
    const int b0    = (xcd * 2 + b_sub) * 256;
    const int e0    = e_t * 128;

    const int t    = threadIdx.x;
    const int l    = t & 63;
    const int w    = t >> 6;            // 0..7
    const int wrow = (w >> 1) * 64;     // 0,64,128,192
    const int wcol = (w & 1) * 64;      // 0,64
    const int l31  = l & 31;
    const int h5   = l >> 5;

    f32x16 acc1[2][2];   // hi*hi
    f32x16 acc2[2][2];   // hi*lo' + lo'*hi  (scale 2^11)
    #pragma unroll
    for (int m = 0; m < 2; ++m)
        #pragma unroll
        for (int n = 0; n < 2; ++n) {
            #pragma unroll
            for (int j = 0; j < 16; ++j) { acc1[m][n][j] = 0.f; acc2[m][n][j] = 0.f; }
        }

    // ---- staging source addressing (pre-swizzled) ----
    // per gload instr: lane l -> local line (l>>3), slot (l&7);
    // source row offset lrow = 2*(l>>3) + (slx>>2), k-granule kg = slx&3, slx = (l&7)^(l>>3)
    const int slx  = (l & 7) ^ (l >> 3);
    const int lrow = 2 * (l >> 3) + (slx >> 2);
    const int kg   = slx & 3;

    const _Float16* gA0h = eh + (size_t)(b0 + 32 * w + lrow) * D_SZ + kg * 8;
    const _Float16* gA1h = gA0h + (size_t)16 * D_SZ;
    const _Float16* gA0l = el + (size_t)(b0 + 32 * w + lrow) * D_SZ + kg * 8;
    const _Float16* gA1l = gA0l + (size_t)16 * D_SZ;
    const _Float16* gBh  = Wh + ((size_t)k * D_SZ + e0 + 16 * w + lrow) * D_SZ + kg * 8;
    const _Float16* gBl  = Wl + ((size_t)k * D_SZ + e0 + 16 * w + lrow) * D_SZ + kg * 8;

    // ---- read offsets (kt-independent; buffer base added per iter) ----
    // row r: line = r>>1, slot = (((r&1)<<2)|kslot) ^ (line&7), kslot = ks*2 + h5
    int aoff[2][2], boff[2][2];
    #pragma unroll
    for (int m = 0; m < 2; ++m) {
        const int r = wrow + m * 32 + l31;
        const int line = r >> 1;
        const int pr = (r & 1) << 2;
        #pragma unroll
        for (int ks = 0; ks < 2; ++ks)
            aoff[m][ks] = line * 128 + (((pr | (ks * 2 + h5)) ^ (line & 7)) << 4);
    }
    #pragma unroll
    for (int n = 0; n < 2; ++n) {
        const int r = wcol + n * 32 + l31;
        const int line = r >> 1;
        const int pr = (r & 1) << 2;
        #pragma unroll
        for (int ks = 0; ks < 2; ++ks)
            boff[n][ks] = line * 128 + (((pr | (ks * 2 + h5)) ^ (line & 7)) << 4);
    }

#define STAGE(bufbase, ktv) do {                                   \
        const size_t kb = (size_t)(ktv) * 32;                      \
        char* bb = (bufbase);                                      \
        GLOAD16(gA0h + kb, bb + w * 2048);                         \
        GLOAD16(gA1h + kb, bb + w * 2048 + 1024);                  \
        GLOAD16(gA0l + kb, bb + 16384 + w * 2048);                 \
        GLOAD16(gA1l + kb, bb + 16384 + w * 2048 + 1024);          \
        GLOAD16(gBh + kb,  bb + 32768 + w * 1024);                 \
        GLOAD16(gBl + kb,  bb + 40960 + w * 1024);                 \
    } while (0)

    // prologue
    STAGE(lds, 0);
    __syncthreads();

    for (int kt = 0; kt < NT; ++kt) {
        if (kt + 1 < NT) {
            STAGE(lds + (((kt + 1) & 1) ? 49152 : 0), kt + 1);
            __builtin_amdgcn_sched_barrier(0);
        }

        const char* bufc = lds + ((kt & 1) ? 49152 : 0);
        #pragma unroll
        for (int ks = 0; ks < 2; ++ks) {
            h16x8 ah[2], al[2], bh[2], bl[2];
            #pragma unroll
            for (int m = 0; m < 2; ++m) {
                ah[m] = *(const h16x8*)(bufc + aoff[m][ks]);
                al[m] = *(const h16x8*)(bufc + 16384 + aoff[m][ks]);
            }
            #pragma unroll
            for (int n = 0; n < 2; ++n) {
                bh[n] = *(const h16x8*)(bufc + 32768 + boff[n][ks]);
                bl[n] = *(const h16x8*)(bufc + 40960 + boff[n][ks]);
            }
            #pragma unroll
            for (int m = 0; m < 2; ++m)
                #pragma unroll
                for (int n = 0; n < 2; ++n) {
                    acc1[m][n] = __builtin_amdgcn_mfma_f32_32x32x16_f16(ah[m], bh[n], acc1[m][n], 0, 0, 0);
                    acc2[m][n] = __builtin_amdgcn_mfma_f32_32x32x16_f16(ah[m], bl[n], acc2[m][n], 0, 0, 0);
                    acc2[m][n] = __builtin_amdgcn_mfma_f32_32x32x16_f16(al[m], bh[n], acc2[m][n], 0, 0, 0);
                }
        }
        __syncthreads();   // vmcnt(0)+lgkmcnt(0)+barrier: next-tile loads drained, cur buffer release
    }
#undef STAGE

    // ---- epilogue: tv = acc1 + acc2/2048; v[j] = sum_n tv * e2 ----
    // 32x32 C/D layout (m74/m101): col = lane&31, row = (rg&3) + 8*(rg>>2) + 4*(lane>>5)
    float v[32];
    #pragma unroll
    for (int j = 0; j < 32; ++j) v[j] = 0.f;

    #pragma unroll
    for (int m = 0; m < 2; ++m) {
        #pragma unroll
        for (int n = 0; n < 2; ++n) {
            const int col = e0 + wcol + n * 32 + l31;
            #pragma unroll
            for (int rg = 0; rg < 16; ++rg) {
                const int row = b0 + wrow + m * 32 + (rg & 3) + 8 * (rg >> 2) + 4 * h5;
                float tv = acc1[m][n][rg] + acc2[m][n][rg] * (1.0f / 2048.0f);
                v[m * 16 + rg] += tv * e2[(size_t)row * D_SZ + col];
            }
        }
    }

    // reduce-scatter across 32 lanes (h5 fixed): 31 shfl, lane ends with index bitrev5(l31)
    #pragma unroll
    for (int s = 0; s < 5; ++s) {
        const int half = 16 >> s;
        const bool hi = (l31 >> s) & 1;
        #pragma unroll
        for (int i = 0; i < half; ++i) {
            float send = hi ? v[i] : v[i + half];
            float recv = __shfl_xor(send, 1 << s, 32);
            v[i] = (hi ? v[i + half] : v[i]) + recv;
        }
    }

    const int j = ((l31 & 1) << 4) | ((l31 & 2) << 2) | (l31 & 4) | ((l31 & 8) >> 2) | ((l31 & 16) >> 4);
    const int row = wrow + (j >> 4) * 32 + (j & 3) + 8 * ((j >> 2) & 3) + 4 * h5;
    atomicAdd(out + (size_t)k * B_SZ + b0 + row, v[0]);
}

// ================= fallback path (round-1 bilinear, used if ws too small) =================
__device__ __forceinline__ int swz_fb(int row, int byte_in_row) {
    int slot = byte_in_row >> 4;
    int in   = byte_in_row & 15;
    return row * 128 + (((slot ^ (row & 7)) << 4) | in);
}
__device__ __forceinline__ void split_fb(float x, unsigned short& h, unsigned short& l) {
    _Float16 hf = (_Float16)x;
    float hff = (float)hf;
    _Float16 lf = (_Float16)((x - hff) * 2048.0f);
    h = __builtin_bit_cast(unsigned short, hf);
    l = __builtin_bit_cast(unsigned short, lf);
}
__global__ __launch_bounds__(256, 2)
void ntl_bilinear_fb(const float* __restrict__ e1, const float* __restrict__ e2,
                     const float* __restrict__ W, float* __restrict__ out) {
    __shared__ __align__(16) char smem[65536];
    char* const Ah = smem;
    char* const Al = smem + 16384;
    char* const Bh = smem + 32768;
    char* const Bl = smem + 49152;
    const int bid = blockIdx.x;
    const int k   = bid >> 8;
    const int rem = bid & 255;
    const int b0  = (rem >> 3) * 128;
    const int e0  = (rem & 7) * 128;
    const int t  = threadIdx.x;
    const int l  = t & 63;
    const int w  = t >> 6;
    const int wr = (w >> 1) * 64;
    const int wc = (w & 1) * 64;
    const int lrow = l & 15;
    const int lq   = l >> 4;
    f32x4 acc1[4][4], acc2[4][4];
    #pragma unroll
    for (int m = 0; m < 4; ++m)
        #pragma unroll
        for (int n = 0; n < 4; ++n) {
            acc1[m][n] = f32x4{0.f, 0.f, 0.f, 0.f};
            acc2[m][n] = f32x4{0.f, 0.f, 0.f, 0.f};
        }
    const int sa_row = t >> 4;
    const int sa_cg  = (t & 15) * 4;
    const int sb_e   = t & 127;
    const int sb_dg  = t >> 7;
    const float* const e1b = e1 + (size_t)b0 * D_SZ;
    const float* const wb  = W + ((size_t)k * D_SZ) * D_SZ + e0 + sb_e;
    for (int kt = 0; kt < 16; ++kt) {
        const int d0 = kt * 64;
        #pragma unroll
        for (int p = 0; p < 8; ++p) {
            const int r = sa_row + p * 16;
            f32x4 vv4 = *(const f32x4*)(e1b + (size_t)r * D_SZ + d0 + sa_cg);
            unsigned short hh[4], ll[4];
            #pragma unroll
            for (int qq = 0; qq < 4; ++qq) split_fb(vv4[qq], hh[qq], ll[qq]);
            u32x2 hv = { (unsigned)hh[0] | ((unsigned)hh[1] << 16),
                         (unsigned)hh[2] | ((unsigned)hh[3] << 16) };
            u32x2 lv = { (unsigned)ll[0] | ((unsigned)ll[1] << 16),
                         (unsigned)ll[2] | ((unsigned)ll[3] << 16) };
            const int ad = swz_fb(r, sa_cg * 2);
            *(u32x2*)(Ah + ad) = hv;
            *(u32x2*)(Al + ad) = lv;
        }
        {
            const float* ws2 = wb + (size_t)(d0 + sb_dg * 32) * D_SZ;
            #pragma unroll
            for (int gg = 0; gg < 4; ++gg) {
                unsigned short hh[8], ll[8];
                #pragma unroll
                for (int i = 0; i < 8; ++i)
                    split_fb(ws2[(size_t)(gg * 8 + i) * D_SZ], hh[i], ll[i]);
                u32x4 hv = { (unsigned)hh[0] | ((unsigned)hh[1] << 16),
                             (unsigned)hh[2] | ((unsigned)hh[3] << 16),
                             (unsigned)hh[4] | ((unsigned)hh[5] << 16),
                             (unsigned)hh[6] | ((unsigned)hh[7] << 16) };
                u32x4 lv = { (unsigned)ll[0] | ((unsigned)ll[1] << 16),
                             (unsigned)ll[2] | ((unsigned)ll[3] << 16),
                             (unsigned)ll[4] | ((unsigned)ll[5] << 16),
                             (unsigned)ll[6] | ((unsigned)ll[7] << 16) };
                const int ad = swz_fb(sb_e, (sb_dg * 32 + gg * 8) * 2);
                *(u32x4*)(Bh + ad) = hv;
                *(u32x4*)(Bl + ad) = lv;
            }
        }
        __syncthreads();
        #pragma unroll
        for (int kk = 0; kk < 2; ++kk) {
            const int kb = kk * 64 + lq * 16;
            h16x8 a_h[4], a_l[4];
            #pragma unroll
            for (int m = 0; m < 4; ++m) {
                const int ad = swz_fb(wr + m * 16 + lrow, kb);
                a_h[m] = *(const h16x8*)(Ah + ad);
                a_l[m] = *(const h16x8*)(Al + ad);
            }
            #pragma unroll
            for (int n = 0; n < 4; ++n) {
                const int bd = swz_fb(wc + n * 16 + lrow, kb);
                h16x8 b_h = *(const h16x8*)(Bh + bd);
                h16x8 b_l = *(const h16x8*)(Bl + bd);
                #pragma unroll
                for (int m = 0; m < 4; ++m) {
                    acc1[m][n] = __builtin_amdgcn_mfma_f32_16x16x32_f16(a_h[m], b_h, acc1[m][n], 0, 0, 0);
                    acc2[m][n] = __builtin_amdgcn_mfma_f32_16x16x32_f16(a_h[m], b_l, acc2[m][n], 0, 0, 0);
                    acc2[m][n] = __builtin_amdgcn_mfma_f32_16x16x32_f16(a_l[m], b_h, acc2[m][n], 0, 0, 0);
                }
            }
        }
        __syncthreads();
    }
    float rsum[16];
    #pragma unroll
    for (int i = 0; i < 16; ++i) rsum[i] = 0.f;
    #pragma unroll
    for (int m = 0; m < 4; ++m) {
        #pragma unroll
        for (int n = 0; n < 4; ++n) {
            const int col = e0 + wc + n * 16 + lrow;
            #pragma unroll
            for (int jq = 0; jq < 4; ++jq) {
                const int row = b0 + wr + m * 16 + lq * 4 + jq;
                float tv = acc1[m][n][jq] + acc2[m][n][jq] * (1.0f / 2048.0f);
                rsum[m * 4 + jq] += tv * e2[(size_t)row * D_SZ + col];
            }
        }
    }
    #pragma unroll
    for (int i = 0; i < 16; ++i) {
        float vv = rsum[i];
        vv += __shfl_xor(vv, 1, 16);
        vv += __shfl_xor(vv, 2, 16);
        vv += __shfl_xor(vv, 4, 16);
        vv += __shfl_xor(vv, 8, 16);
        if (lrow == 0) {
            const int row = b0 + wr + (i >> 2) * 16 + lq * 4 + (i & 3);
            atomicAdd(out + (size_t)k * B_SZ + row, vv);
        }
    }
}

// ---------------- ff / sumb / tanh ----------------
__global__ __launch_bounds__(256)
void ntl_ff(const float* __restrict__ e1, const float* __restrict__ e2,
            const float* __restrict__ V, float* __restrict__ out) {
    __shared__ float vt[32 * 258];
    const int t  = threadIdx.x;
    const int c  = t & 31;
    const int rl = t >> 5;
    const int r  = blockIdx.x * 8 + rl;
    float acc = 0.f;
    for (int j0 = 0; j0 < 2 * D_SZ; j0 += 256) {
        __syncthreads();
        #pragma unroll
        for (int i = 0; i < 32; ++i) {
            const int f = i * 256 + t;
            vt[(f & 31) * 258 + (f >> 5)] = V[(size_t)j0 * K_SZ + f];
        }
        __syncthreads();
        const float* src = (j0 < D_SZ) ? (e1 + (size_t)r * D_SZ + j0)
                                       : (e2 + (size_t)r * D_SZ + (j0 - D_SZ));
        #pragma unroll 8
        for (int jj = 0; jj < 256; jj += 2) {
            f32x2 a  = *(const f32x2*)(src + jj);
            f32x2 vv = *(const f32x2*)(&vt[c * 258 + jj]);
            acc += a[0] * vv[0] + a[1] * vv[1];
        }
    }
    out[(size_t)r * K_SZ + c] += acc;
}

__global__ void ntl_sumb(const float* __restrict__ b, float* __restrict__ ws) {
    __shared__ float red[256];
    const int t = threadIdx.x;
    red[t] = b[t] + b[t + 256] + b[t + 512] + b[t + 768];
    __syncthreads();
    for (int s = 128; s > 0; s >>= 1) {
        if (t < s) red[t] += red[t + s];
        __syncthreads();
    }
    if (t == 0) ws[0] = red[0];
}

__global__ void ntl_tanh(float* __restrict__ out, const float* __restrict__ ws) {
    const int p = blockIdx.x * 256 + threadIdx.x;
    out[p] = tanhf(out[p] + ws[0]);
}

extern "C" void kernel_launch(void* const* d_in, const int* in_sizes, int n_in,
                              void* d_out, int out_size, void* d_ws, size_t ws_size,
                              hipStream_t stream) {
    const float* e1 = (const float*)d_in[0];
    const float* e2 = (const float*)d_in[1];
    const float* W  = (const float*)d_in[2];
    const float* V  = (const float*)d_in[3];
    const float* b  = (const float*)d_in[4];
    float* out = (float*)d_out;

    const size_t WT = (size_t)K_SZ * D_SZ * D_SZ;
    const size_t ET = (size_t)B_SZ * D_SZ;
    const size_t need = (2 * WT + 2 * ET) * sizeof(_Float16) + 16;

    hipMemsetAsync(d_out, 0, (size_t)B_SZ * K_SZ * sizeof(float), stream);

    if (ws_size >= need) {
        _Float16* Wh = (_Float16*)d_ws;
        _Float16* Wl = Wh + WT;
        _Float16* ehp = Wl + WT;
        _Float16* elp = ehp + ET;
        float* sb = (float*)(elp + ET);
        ntl_sumb<<<1, 256, 0, stream>>>(b, sb);
        ntl_prep_w<<<dim3(K_SZ * 256), dim3(256), 0, stream>>>(W, Wh, Wl);
        ntl_prep_e<<<dim3((int)(ET / 1024)), dim3(256), 0, stream>>>(e1, ehp, elp);
        // grid: 8 xcd x (8 e_t x 2 b_sub x 32 k) = 4096 blocks
        ntl_bilinear5<<<dim3(4096), dim3(512), 0, stream>>>(ehp, elp, Wh, Wl, e2, out);
        ntl_ff<<<dim3(B_SZ / 8), dim3(256), 0, stream>>>(e1, e2, V, out);
        ntl_tanh<<<dim3((B_SZ * K_SZ) / 256), dim3(256), 0, stream>>>(out, sb);
    } else {
        float* sb = (float*)d_ws;
        ntl_sumb<<<1, 256, 0, stream>>>(b, sb);
        ntl_bilinear_fb<<<dim3(K_SZ * 256), dim3(256), 0, stream>>>(e1, e2, W, out);
        ntl_ff<<<dim3(B_SZ / 8), dim3(256), 0, stream>>>(e1, e2, V, out);
        ntl_tanh<<<dim3((B_SZ * K_SZ) / 256), dim3(256), 0, stream>>>(out, sb);
    }
}

// Round 7
// 920.332 us; speedup vs baseline: 1.2115x; 1.2115x over previous
//
#include <hip/hip_runtime.h>

#define B_SZ 4096
#define D_SZ 1024
#define K_SZ 32
#define NT   32          // K-depth steps of 32

typedef _Float16 h16x8 __attribute__((ext_vector_type(8)));
typedef float f32x4 __attribute__((ext_vector_type(4)));
typedef float f32x2 __attribute__((ext_vector_type(2)));
typedef unsigned int u32x2 __attribute__((ext_vector_type(2)));
typedef unsigned int u32x4 __attribute__((ext_vector_type(4)));
typedef unsigned short u16x4 __attribute__((ext_vector_type(4)));

// async global->LDS, 16B per lane (wave-uniform LDS base + lane*16)
#define GLOAD16(gp, sp) __builtin_amdgcn_global_load_lds( \
    (const __attribute__((address_space(1))) void*)(gp),  \
    (__attribute__((address_space(3))) void*)(sp), 16, 0, 0)

// fp32 -> fp16 hi + fp16 lo*2^11 (lo scaled to stay normal)
__device__ __forceinline__ void split1(float x, _Float16& h, _Float16& l) {
    h = (_Float16)x;
    l = (_Float16)((x - (float)h) * 2048.0f);
}

// ---------------- prepass: W[k][d][e] f32 -> Wt_h/Wt_l[k][e][d] fp16 ----------------
__global__ __launch_bounds__(256)
void ntl_prep_w(const float* __restrict__ W,
                _Float16* __restrict__ Wh, _Float16* __restrict__ Wl) {
    __shared__ float tile[64 * 69];
    const int bid = blockIdx.x;
    const int k  = bid >> 8;
    const int d0 = ((bid >> 4) & 15) << 6;
    const int e0 = (bid & 15) << 6;
    const int t  = threadIdx.x;
    const int r  = t >> 4;
    const int c4 = (t & 15) << 2;

    const float* src = W + ((size_t)k * D_SZ + d0) * D_SZ + e0;
    #pragma unroll
    for (int p = 0; p < 4; ++p) {
        f32x4 v = *(const f32x4*)(src + (size_t)(p * 16 + r) * D_SZ + c4);
        float* dst = &tile[(p * 16 + r) * 69 + c4];
        dst[0] = v[0]; dst[1] = v[1]; dst[2] = v[2]; dst[3] = v[3];
    }
    __syncthreads();
    #pragma unroll
    for (int p = 0; p < 4; ++p) {
        const int e = p * 16 + r;
        u16x4 hh, ll;
        #pragma unroll
        for (int q = 0; q < 4; ++q) {
            float v = tile[(c4 + q) * 69 + e];
            _Float16 h, l;
            split1(v, h, l);
            hh[q] = __builtin_bit_cast(unsigned short, h);
            ll[q] = __builtin_bit_cast(unsigned short, l);
        }
        const size_t o = ((size_t)k * D_SZ + e0 + e) * D_SZ + d0 + c4;
        *(u16x4*)(Wh + o) = hh;
        *(u16x4*)(Wl + o) = ll;
    }
}

// ---------------- prepass: e1 f32 -> e1_h/e1_l fp16 ----------------
__global__ __launch_bounds__(256)
void ntl_prep_e(const float* __restrict__ e1,
                _Float16* __restrict__ eh, _Float16* __restrict__ el) {
    const size_t i = ((size_t)blockIdx.x * 256 + threadIdx.x) * 4;
    f32x4 v = *(const f32x4*)(e1 + i);
    u16x4 hh, ll;
    #pragma unroll
    for (int q = 0; q < 4; ++q) {
        _Float16 h, l;
        split1(v[q], h, l);
        hh[q] = __builtin_bit_cast(unsigned short, h);
        ll[q] = __builtin_bit_cast(unsigned short, l);
    }
    *(u16x4*)(eh + i) = hh;
    *(u16x4*)(el + i) = ll;
}

// ---------------- main bilinear: 128x128, BK=32, 4 waves, counted-vmcnt dbuf ----------
// LDS 64KB = 2 bufs x 32KB. Buffer: A [0,16K) = 128 lines x 128B {h 64B | l 64B},
// B [16K,32K) same for W[k] e-rows. Slot content c = slot ^ (line&7), c = hl*4 + lq.
// All staging via global_load_lds (linear dest; per-lane source encodes the swizzle +
// h/l base select). 2 blocks/CU (cross-block overlap) + counted vmcnt(8): stage(t+2)
// issued after compute(t) into the buffer compute(t) just released; only stage(t)
// awaited at iter t -> no full drain in the main loop.
__global__ __launch_bounds__(256, 2)
void ntl_bilinear6(const _Float16* __restrict__ eh, const _Float16* __restrict__ el,
                   const _Float16* __restrict__ Wh, const _Float16* __restrict__ Wl,
                   const float* __restrict__ e2, float* __restrict__ out) {
    __shared__ __align__(16) char lds[65536];

    const int bid = blockIdx.x;
    const int k   = bid >> 8;          // 256 blocks per k (W[k] stays hot in L2)
    const int rem = bid & 255;
    const int b0  = (rem >> 3) * 128;  // 32 b-tiles
    const int e0  = (rem & 7) * 128;   // 8 e-tiles

    const int t  = threadIdx.x;
    const int l  = t & 63;
    const int w  = t >> 6;             // 0..3
    const int wr = (w >> 1) * 64;
    const int wc = (w & 1) * 64;
    const int lrow = l & 15;
    const int lq   = l >> 4;           // 0..3

    f32x4 acc1[4][4];   // hi*hi
    f32x4 acc2[4][4];   // hi*lo' + lo'*hi  (scale 2^11)
    #pragma unroll
    for (int m = 0; m < 4; ++m)
        #pragma unroll
        for (int n = 0; n < 4; ++n) {
            acc1[m][n] = f32x4{0.f, 0.f, 0.f, 0.f};
            acc2[m][n] = f32x4{0.f, 0.f, 0.f, 0.f};
        }

    // ---- staging source addressing ----
    // instr i of wave w covers lines w*32 + i*8 + (l>>3); lane slot = l&7;
    // content sx = (l&7) ^ (l>>3):  hl = sx>>2 (base select), lq_s = sx&3 (k-granule)
    const int sline = l >> 3;
    const int sx    = (l & 7) ^ sline;
    const int hl    = sx >> 2;
    const int lqs   = sx & 3;

    const _Float16* aBase = hl ? el : eh;
    const _Float16* bBase = hl ? Wl : Wh;
    const _Float16* gA[4];
    const _Float16* gB[4];
    #pragma unroll
    for (int i = 0; i < 4; ++i) {
        const int row = w * 32 + i * 8 + sline;
        gA[i] = aBase + (size_t)(b0 + row) * D_SZ + lqs * 8;
        gB[i] = bBase + ((size_t)k * D_SZ + e0 + row) * D_SZ + lqs * 8;
    }
    // LDS dests (wave-uniform base + lane*16 implicit)
    const int sOff = w * 32 * 128;     // byte offset of wave's first line

#define STAGE(bufsel, ktv) do {                                          \
        char* bb = lds + ((bufsel) ? 32768 : 0);                         \
        const size_t kb = (size_t)(ktv) * 32;                            \
        GLOAD16(gA[0] + kb, bb + sOff);                                  \
        GLOAD16(gA[1] + kb, bb + sOff + 1024);                           \
        GLOAD16(gA[2] + kb, bb + sOff + 2048);                           \
        GLOAD16(gA[3] + kb, bb + sOff + 3072);                           \
        GLOAD16(gB[0] + kb, bb + 16384 + sOff);                          \
        GLOAD16(gB[1] + kb, bb + 16384 + sOff + 1024);                   \
        GLOAD16(gB[2] + kb, bb + 16384 + sOff + 2048);                   \
        GLOAD16(gB[3] + kb, bb + 16384 + sOff + 3072);                   \
    } while (0)

    // ---- ds_read offsets (R2-verified conflict-free family) ----
    // content c read at slot (c ^ (r&7)); a_h: c=lq, a_l: c=4|lq (within line)
    int aoffH[4], aoffL[4], boffH[4], boffL[4];
    #pragma unroll
    for (int m = 0; m < 4; ++m) {
        const int r = wr + m * 16 + lrow;
        aoffH[m] = r * 128 + ((lq       ^ (r & 7)) << 4);
        aoffL[m] = r * 128 + (((4 | lq) ^ (r & 7)) << 4);
    }
    #pragma unroll
    for (int n = 0; n < 4; ++n) {
        const int r = wc + n * 16 + lrow;
        boffH[n] = 16384 + r * 128 + ((lq       ^ (r & 7)) << 4);
        boffL[n] = 16384 + r * 128 + (((4 | lq) ^ (r & 7)) << 4);
    }

    // prologue: stage t=0 -> buf0, t=1 -> buf1  (16 outstanding)
    STAGE(0, 0);
    STAGE(1, 1);

    for (int kt = 0; kt < NT; ++kt) {
        if (kt < NT - 1) {
            asm volatile("s_waitcnt vmcnt(8)" ::: "memory");   // S(kt) landed; S(kt+1) in flight
        } else {
            asm volatile("s_waitcnt vmcnt(0)" ::: "memory");
        }
        __builtin_amdgcn_sched_barrier(0);
        __builtin_amdgcn_s_barrier();                          // collective: buf(kt) ready
        __builtin_amdgcn_sched_barrier(0);

        const char* buf = lds + ((kt & 1) ? 32768 : 0);

        h16x8 a_h[4], a_l[4];
        #pragma unroll
        for (int m = 0; m < 4; ++m) {
            a_h[m] = *(const h16x8*)(buf + aoffH[m]);
            a_l[m] = *(const h16x8*)(buf + aoffL[m]);
        }
        #pragma unroll
        for (int n = 0; n < 4; ++n) {
            h16x8 b_h = *(const h16x8*)(buf + boffH[n]);
            h16x8 b_l = *(const h16x8*)(buf + boffL[n]);
            #pragma unroll
            for (int m = 0; m < 4; ++m) {
                acc1[m][n] = __builtin_amdgcn_mfma_f32_16x16x32_f16(a_h[m], b_h, acc1[m][n], 0, 0, 0);
                acc2[m][n] = __builtin_amdgcn_mfma_f32_16x16x32_f16(a_h[m], b_l, acc2[m][n], 0, 0, 0);
                acc2[m][n] = __builtin_amdgcn_mfma_f32_16x16x32_f16(a_l[m], b_h, acc2[m][n], 0, 0, 0);
            }
        }

        __builtin_amdgcn_sched_barrier(0);
        __builtin_amdgcn_s_barrier();                          // all waves done reading buf(kt)
        __builtin_amdgcn_sched_barrier(0);

        if (kt + 2 < NT) {
            // S(kt+2) belongs in buf((kt+2)&1) == buf(kt&1) — the buffer
            // compute(kt) just released. (R6 bug: staged the opposite buffer.)
            STAGE(kt & 1, kt + 2);
            __builtin_amdgcn_sched_barrier(0);
        }
    }
#undef STAGE

    // ---- epilogue: T .* e2, reduce over this block's 128 e-columns ----
    // C/D layout (m89): col = lane&15, row = (lane>>4)*4 + j
    float rsum[16];
    #pragma unroll
    for (int i = 0; i < 16; ++i) rsum[i] = 0.f;

    #pragma unroll
    for (int m = 0; m < 4; ++m) {
        #pragma unroll
        for (int n = 0; n < 4; ++n) {
            const int col = e0 + wc + n * 16 + lrow;
            #pragma unroll
            for (int j = 0; j < 4; ++j) {
                const int row = b0 + wr + m * 16 + lq * 4 + j;
                float tv = acc1[m][n][j] + acc2[m][n][j] * (1.0f / 2048.0f);
                rsum[m * 4 + j] += tv * e2[(size_t)row * D_SZ + col];
            }
        }
    }

    #pragma unroll
    for (int i = 0; i < 16; ++i) {
        float v = rsum[i];
        v += __shfl_xor(v, 1, 16);
        v += __shfl_xor(v, 2, 16);
        v += __shfl_xor(v, 4, 16);
        v += __shfl_xor(v, 8, 16);
        if (lrow == 0) {
            const int row = b0 + wr + (i >> 2) * 16 + lq * 4 + (i & 3);
            atomicAdd(out + (size_t)k * B_SZ + row, v);
        }
    }
}

// ================= fallback path (round-1 bilinear, used if ws too small) =================
__device__ __forceinline__ int swz_fb(int row, int byte_in_row) {
    int slot = byte_in_row >> 4;
    int in   = byte_in_row & 15;
    return row * 128 + (((slot ^ (row & 7)) << 4) | in);
}
__device__ __forceinline__ void split_fb(float x, unsigned short& h, unsigned short& l) {
    _Float16 hf = (_Float16)x;
    float hff = (float)hf;
    _Float16 lf = (_Float16)((x - hff) * 2048.0f);
    h = __builtin_bit_cast(unsigned short, hf);
    l = __builtin_bit_cast(unsigned short, lf);
}
__global__ __launch_bounds__(256, 2)
void ntl_bilinear_fb(const float* __restrict__ e1, const float* __restrict__ e2,
                     const float* __restrict__ W, float* __restrict__ out) {
    __shared__ __align__(16) char smem[65536];
    char* const Ah = smem;
    char* const Al = smem + 16384;
    char* const Bh = smem + 32768;
    char* const Bl = smem + 49152;
    const int bid = blockIdx.x;
    const int k   = bid >> 8;
    const int rem = bid & 255;
    const int b0  = (rem >> 3) * 128;
    const int e0  = (rem & 7) * 128;
    const int t  = threadIdx.x;
    const int l  = t & 63;
    const int w  = t >> 6;
    const int wr = (w >> 1) * 64;
    const int wc = (w & 1) * 64;
    const int lrow = l & 15;
    const int lq   = l >> 4;
    f32x4 acc1[4][4], acc2[4][4];
    #pragma unroll
    for (int m = 0; m < 4; ++m)
        #pragma unroll
        for (int n = 0; n < 4; ++n) {
            acc1[m][n] = f32x4{0.f, 0.f, 0.f, 0.f};
            acc2[m][n] = f32x4{0.f, 0.f, 0.f, 0.f};
        }
    const int sa_row = t >> 4;
    const int sa_cg  = (t & 15) * 4;
    const int sb_e   = t & 127;
    const int sb_dg  = t >> 7;
    const float* const e1b = e1 + (size_t)b0 * D_SZ;
    const float* const wb  = W + ((size_t)k * D_SZ) * D_SZ + e0 + sb_e;
    for (int kt = 0; kt < 16; ++kt) {
        const int d0 = kt * 64;
        #pragma unroll
        for (int p = 0; p < 8; ++p) {
            const int r = sa_row + p * 16;
            f32x4 vv4 = *(const f32x4*)(e1b + (size_t)r * D_SZ + d0 + sa_cg);
            unsigned short hh[4], ll[4];
            #pragma unroll
            for (int qq = 0; qq < 4; ++qq) split_fb(vv4[qq], hh[qq], ll[qq]);
            u32x2 hv = { (unsigned)hh[0] | ((unsigned)hh[1] << 16),
                         (unsigned)hh[2] | ((unsigned)hh[3] << 16) };
            u32x2 lv = { (unsigned)ll[0] | ((unsigned)ll[1] << 16),
                         (unsigned)ll[2] | ((unsigned)ll[3] << 16) };
            const int ad = swz_fb(r, sa_cg * 2);
            *(u32x2*)(Ah + ad) = hv;
            *(u32x2*)(Al + ad) = lv;
        }
        {
            const float* ws2 = wb + (size_t)(d0 + sb_dg * 32) * D_SZ;
            #pragma unroll
            for (int gg = 0; gg < 4; ++gg) {
                unsigned short hh[8], ll[8];
                #pragma unroll
                for (int i = 0; i < 8; ++i)
                    split_fb(ws2[(size_t)(gg * 8 + i) * D_SZ], hh[i], ll[i]);
                u32x4 hv = { (unsigned)hh[0] | ((unsigned)hh[1] << 16),
                             (unsigned)hh[2] | ((unsigned)hh[3] << 16),
                             (unsigned)hh[4] | ((unsigned)hh[5] << 16),
                             (unsigned)hh[6] | ((unsigned)hh[7] << 16) };
                u32x4 lv = { (unsigned)ll[0] | ((unsigned)ll[1] << 16),
                             (unsigned)ll[2] | ((unsigned)ll[3] << 16),
                             (unsigned)ll[4] | ((unsigned)ll[5] << 16),
                             (unsigned)ll[6] | ((unsigned)ll[7] << 16) };
                const int ad = swz_fb(sb_e, (sb_dg * 32 + gg * 8) * 2);
                *(u32x4*)(Bh + ad) = hv;
                *(u32x4*)(Bl + ad) = lv;
            }
        }
        __syncthreads();
        #pragma unroll
        for (int kk = 0; kk < 2; ++kk) {
            const int kb = kk * 64 + lq * 16;
            h16x8 a_h[4], a_l[4];
            #pragma unroll
            for (int m = 0; m < 4; ++m) {
                const int ad = swz_fb(wr + m * 16 + lrow, kb);
                a_h[m] = *(const h16x8*)(Ah + ad);
                a_l[m] = *(const h16x8*)(Al + ad);
            }
            #pragma unroll
            for (int n = 0; n < 4; ++n) {
                const int bd = swz_fb(wc + n * 16 + lrow, kb);
                h16x8 b_h = *(const h16x8*)(Bh + bd);
                h16x8 b_l = *(const h16x8*)(Bl + bd);
                #pragma unroll
                for (int m = 0; m < 4; ++m) {
                    acc1[m][n] = __builtin_amdgcn_mfma_f32_16x16x32_f16(a_h[m], b_h, acc1[m][n], 0, 0, 0);
                    acc2[m][n] = __builtin_amdgcn_mfma_f32_16x16x32_f16(a_h[m], b_l, acc2[m][n], 0, 0, 0);
                    acc2[m][n] = __builtin_amdgcn_mfma_f32_16x16x32_f16(a_l[m], b_h, acc2[m][n], 0, 0, 0);
                }
            }
        }
        __syncthreads();
    }
    float rsum[16];
    #pragma unroll
    for (int i = 0; i < 16; ++i) rsum[i] = 0.f;
    #pragma unroll
    for (int m = 0; m < 4; ++m) {
        #pragma unroll
        for (int n = 0; n < 4; ++n) {
            const int col = e0 + wc + n * 16 + lrow;
            #pragma unroll
            for (int jq = 0; jq < 4; ++jq) {
                const int row = b0 + wr + m * 16 + lq * 4 + jq;
                float tv = acc1[m][n][jq] + acc2[m][n][jq] * (1.0f / 2048.0f);
                rsum[m * 4 + jq] += tv * e2[(size_t)row * D_SZ + col];
            }
        }
    }
    #pragma unroll
    for (int i = 0; i < 16; ++i) {
        float vv = rsum[i];
        vv += __shfl_xor(vv, 1, 16);
        vv += __shfl_xor(vv, 2, 16);
        vv += __shfl_xor(vv, 4, 16);
        vv += __shfl_xor(vv, 8, 16);
        if (lrow == 0) {
            const int row = b0 + wr + (i >> 2) * 16 + lq * 4 + (i & 3);
            atomicAdd(out + (size_t)k * B_SZ + row, vv);
        }
    }
}

// ---------------- ff / sumb / tanh ----------------
__global__ __launch_bounds__(256)
void ntl_ff(const float* __restrict__ e1, const float* __restrict__ e2,
            const float* __restrict__ V, float* __restrict__ out) {
    __shared__ float vt[32 * 258];
    const int t  = threadIdx.x;
    const int c  = t & 31;
    const int rl = t >> 5;
    const int r  = blockIdx.x * 8 + rl;
    float acc = 0.f;
    for (int j0 = 0; j0 < 2 * D_SZ; j0 += 256) {
        __syncthreads();
        #pragma unroll
        for (int i = 0; i < 32; ++i) {
            const int f = i * 256 + t;
            vt[(f & 31) * 258 + (f >> 5)] = V[(size_t)j0 * K_SZ + f];
        }
        __syncthreads();
        const float* src = (j0 < D_SZ) ? (e1 + (size_t)r * D_SZ + j0)
                                       : (e2 + (size_t)r * D_SZ + (j0 - D_SZ));
        #pragma unroll 8
        for (int jj = 0; jj < 256; jj += 2) {
            f32x2 a  = *(const f32x2*)(src + jj);
            f32x2 vv = *(const f32x2*)(&vt[c * 258 + jj]);
            acc += a[0] * vv[0] + a[1] * vv[1];
        }
    }
    out[(size_t)r * K_SZ + c] += acc;
}

__global__ void ntl_sumb(const float* __restrict__ b, float* __restrict__ ws) {
    __shared__ float red[256];
    const int t = threadIdx.x;
    red[t] = b[t] + b[t + 256] + b[t + 512] + b[t + 768];
    __syncthreads();
    for (int s = 128; s > 0; s >>= 1) {
        if (t < s) red[t] += red[t + s];
        __syncthreads();
    }
    if (t == 0) ws[0] = red[0];
}

__global__ void ntl_tanh(float* __restrict__ out, const float* __restrict__ ws) {
    const int p = blockIdx.x * 256 + threadIdx.x;
    out[p] = tanhf(out[p] + ws[0]);
}

extern "C" void kernel_launch(void* const* d_in, const int* in_sizes, int n_in,
                              void* d_out, int out_size, void* d_ws, size_t ws_size,
                              hipStream_t stream) {
    const float* e1 = (const float*)d_in[0];
    const float* e2 = (const float*)d_in[1];
    const float* W  = (const float*)d_in[2];
    const float* V  = (const float*)d_in[3];
    const float* b  = (const float*)d_in[4];
    float* out = (float*)d_out;

    const size_t WT = (size_t)K_SZ * D_SZ * D_SZ;
    const size_t ET = (size_t)B_SZ * D_SZ;
    const size_t need = (2 * WT + 2 * ET) * sizeof(_Float16) + 16;

    hipMemsetAsync(d_out, 0, (size_t)B_SZ * K_SZ * sizeof(float), stream);

    if (ws_size >= need) {
        _Float16* Wh = (_Float16*)d_ws;
        _Float16* Wl = Wh + WT;
        _Float16* ehp = Wl + WT;
        _Float16* elp = ehp + ET;
        float* sb = (float*)(elp + ET);
        ntl_sumb<<<1, 256, 0, stream>>>(b, sb);
        ntl_prep_w<<<dim3(K_SZ * 256), dim3(256), 0, stream>>>(W, Wh, Wl);
        ntl_prep_e<<<dim3((int)(ET / 1024)), dim3(256), 0, stream>>>(e1, ehp, elp);
        ntl_bilinear6<<<dim3(K_SZ * 256), dim3(256), 0, stream>>>(ehp, elp, Wh, Wl, e2, out);
        ntl_ff<<<dim3(B_SZ / 8), dim3(256), 0, stream>>>(e1, e2, V, out);
        ntl_tanh<<<dim3((B_SZ * K_SZ) / 256), dim3(256), 0, stream>>>(out, sb);
    } else {
        float* sb = (float*)d_ws;
        ntl_sumb<<<1, 256, 0, stream>>>(b, sb);
        ntl_bilinear_fb<<<dim3(K_SZ * 256), dim3(256), 0, stream>>>(e1, e2, W, out);
        ntl_ff<<<dim3(B_SZ / 8), dim3(256), 0, stream>>>(e1, e2, V, out);
        ntl_tanh<<<dim3((B_SZ * K_SZ) / 256), dim3(256), 0, stream>>>(out, sb);
    }
}

// Round 8
// 848.020 us; speedup vs baseline: 1.3148x; 1.0853x over previous
//
#include <hip/hip_runtime.h>

#define B_SZ 4096
#define D_SZ 1024
#define K_SZ 32
#define NT   32          // K-depth steps of 32

typedef _Float16 h16x8 __attribute__((ext_vector_type(8)));
typedef float f32x4 __attribute__((ext_vector_type(4)));
typedef float f32x2 __attribute__((ext_vector_type(2)));
typedef unsigned int u32x2 __attribute__((ext_vector_type(2)));
typedef unsigned int u32x4 __attribute__((ext_vector_type(4)));
typedef unsigned short u16x4 __attribute__((ext_vector_type(4)));

// async global->LDS, 16B per lane (wave-uniform LDS base + lane*16)
#define GLOAD16(gp, sp) __builtin_amdgcn_global_load_lds( \
    (const __attribute__((address_space(1))) void*)(gp),  \
    (__attribute__((address_space(3))) void*)(sp), 16, 0, 0)

// fp32 -> fp16 hi + fp16 lo*2^11 (lo scaled to stay normal)
__device__ __forceinline__ void split1(float x, _Float16& h, _Float16& l) {
    h = (_Float16)x;
    l = (_Float16)((x - (float)h) * 2048.0f);
}

// ---------------- prepass: W[k][d][e] f32 -> Wt_h/Wt_l[k][e][d] fp16 ----------------
__global__ __launch_bounds__(256)
void ntl_prep_w(const float* __restrict__ W,
                _Float16* __restrict__ Wh, _Float16* __restrict__ Wl) {
    __shared__ float tile[64 * 69];
    const int bid = blockIdx.x;
    const int k  = bid >> 8;
    const int d0 = ((bid >> 4) & 15) << 6;
    const int e0 = (bid & 15) << 6;
    const int t  = threadIdx.x;
    const int r  = t >> 4;
    const int c4 = (t & 15) << 2;

    const float* src = W + ((size_t)k * D_SZ + d0) * D_SZ + e0;
    #pragma unroll
    for (int p = 0; p < 4; ++p) {
        f32x4 v = *(const f32x4*)(src + (size_t)(p * 16 + r) * D_SZ + c4);
        float* dst = &tile[(p * 16 + r) * 69 + c4];
        dst[0] = v[0]; dst[1] = v[1]; dst[2] = v[2]; dst[3] = v[3];
    }
    __syncthreads();
    #pragma unroll
    for (int p = 0; p < 4; ++p) {
        const int e = p * 16 + r;
        u16x4 hh, ll;
        #pragma unroll
        for (int q = 0; q < 4; ++q) {
            float v = tile[(c4 + q) * 69 + e];
            _Float16 h, l;
            split1(v, h, l);
            hh[q] = __builtin_bit_cast(unsigned short, h);
            ll[q] = __builtin_bit_cast(unsigned short, l);
        }
        const size_t o = ((size_t)k * D_SZ + e0 + e) * D_SZ + d0 + c4;
        *(u16x4*)(Wh + o) = hh;
        *(u16x4*)(Wl + o) = ll;
    }
}

// ---------------- prepass: e1 f32 -> e1_h/e1_l fp16 ----------------
__global__ __launch_bounds__(256)
void ntl_prep_e(const float* __restrict__ e1,
                _Float16* __restrict__ eh, _Float16* __restrict__ el) {
    const size_t i = ((size_t)blockIdx.x * 256 + threadIdx.x) * 4;
    f32x4 v = *(const f32x4*)(e1 + i);
    u16x4 hh, ll;
    #pragma unroll
    for (int q = 0; q < 4; ++q) {
        _Float16 h, l;
        split1(v[q], h, l);
        hh[q] = __builtin_bit_cast(unsigned short, h);
        ll[q] = __builtin_bit_cast(unsigned short, l);
    }
    *(u16x4*)(eh + i) = hh;
    *(u16x4*)(el + i) = ll;
}

// ---------------- main bilinear: 128x128, BK=32, 4 waves, counted-vmcnt dbuf ----------
// Identical schedule to R7 (refcheck'd). ONE change: XCD-aware work placement.
// xcd = bid&7 owns b-tiles [xcd*4, xcd*4+4): its A-panels (2MB) stay L2-resident
// across all k; per-XCD sequence k -> e -> bl(inner) makes the 4 consumers of each
// W[k] e-slice adjacent in dispatch order (1 fetch + 3 L2 hits).
__global__ __launch_bounds__(256, 2)
void ntl_bilinear7(const _Float16* __restrict__ eh, const _Float16* __restrict__ el,
                   const _Float16* __restrict__ Wh, const _Float16* __restrict__ Wl,
                   const float* __restrict__ e2, float* __restrict__ out) {
    __shared__ __align__(16) char lds[65536];

    const int bid = blockIdx.x;
    const int xcd = bid & 7;           // HW round-robin: bid%8 -> XCD
    const int seq = bid >> 3;          // 0..1023, in-order within an XCD
    const int k   = seq >> 5;          // 32 (slowest: W[k] streams once)
    const int e_t = (seq >> 2) & 7;    // 8 e-tiles
    const int bl  = seq & 3;           // 4 b-tiles per XCD (innermost)
    const int b0  = (xcd * 4 + bl) * 128;
    const int e0  = e_t * 128;

    const int t  = threadIdx.x;
    const int l  = t & 63;
    const int w  = t >> 6;             // 0..3
    const int wr = (w >> 1) * 64;
    const int wc = (w & 1) * 64;
    const int lrow = l & 15;
    const int lq   = l >> 4;           // 0..3

    f32x4 acc1[4][4];   // hi*hi
    f32x4 acc2[4][4];   // hi*lo' + lo'*hi  (scale 2^11)
    #pragma unroll
    for (int m = 0; m < 4; ++m)
        #pragma unroll
        for (int n = 0; n < 4; ++n) {
            acc1[m][n] = f32x4{0.f, 0.f, 0.f, 0.f};
            acc2[m][n] = f32x4{0.f, 0.f, 0.f, 0.f};
        }

    // ---- staging source addressing ----
    // instr i of wave w covers lines w*32 + i*8 + (l>>3); lane slot = l&7;
    // content sx = (l&7) ^ (l>>3):  hl = sx>>2 (base select), lq_s = sx&3 (k-granule)
    const int sline = l >> 3;
    const int sx    = (l & 7) ^ sline;
    const int hl    = sx >> 2;
    const int lqs   = sx & 3;

    const _Float16* aBase = hl ? el : eh;
    const _Float16* bBase = hl ? Wl : Wh;
    const _Float16* gA[4];
    const _Float16* gB[4];
    #pragma unroll
    for (int i = 0; i < 4; ++i) {
        const int row = w * 32 + i * 8 + sline;
        gA[i] = aBase + (size_t)(b0 + row) * D_SZ + lqs * 8;
        gB[i] = bBase + ((size_t)k * D_SZ + e0 + row) * D_SZ + lqs * 8;
    }
    // LDS dests (wave-uniform base + lane*16 implicit)
    const int sOff = w * 32 * 128;     // byte offset of wave's first line

#define STAGE(bufsel, ktv) do {                                          \
        char* bb = lds + ((bufsel) ? 32768 : 0);                         \
        const size_t kb = (size_t)(ktv) * 32;                            \
        GLOAD16(gA[0] + kb, bb + sOff);                                  \
        GLOAD16(gA[1] + kb, bb + sOff + 1024);                           \
        GLOAD16(gA[2] + kb, bb + sOff + 2048);                           \
        GLOAD16(gA[3] + kb, bb + sOff + 3072);                           \
        GLOAD16(gB[0] + kb, bb + 16384 + sOff);                          \
        GLOAD16(gB[1] + kb, bb + 16384 + sOff + 1024);                   \
        GLOAD16(gB[2] + kb, bb + 16384 + sOff + 2048);                   \
        GLOAD16(gB[3] + kb, bb + 16384 + sOff + 3072);                   \
    } while (0)

    // ---- ds_read offsets (R2-verified conflict-free family) ----
    // content c read at slot (c ^ (r&7)); a_h: c=lq, a_l: c=4|lq (within line)
    int aoffH[4], aoffL[4], boffH[4], boffL[4];
    #pragma unroll
    for (int m = 0; m < 4; ++m) {
        const int r = wr + m * 16 + lrow;
        aoffH[m] = r * 128 + ((lq       ^ (r & 7)) << 4);
        aoffL[m] = r * 128 + (((4 | lq) ^ (r & 7)) << 4);
    }
    #pragma unroll
    for (int n = 0; n < 4; ++n) {
        const int r = wc + n * 16 + lrow;
        boffH[n] = 16384 + r * 128 + ((lq       ^ (r & 7)) << 4);
        boffL[n] = 16384 + r * 128 + (((4 | lq) ^ (r & 7)) << 4);
    }

    // prologue: stage t=0 -> buf0, t=1 -> buf1  (16 outstanding)
    STAGE(0, 0);
    STAGE(1, 1);

    for (int kt = 0; kt < NT; ++kt) {
        if (kt < NT - 1) {
            asm volatile("s_waitcnt vmcnt(8)" ::: "memory");   // S(kt) landed; S(kt+1) in flight
        } else {
            asm volatile("s_waitcnt vmcnt(0)" ::: "memory");
        }
        __builtin_amdgcn_sched_barrier(0);
        __builtin_amdgcn_s_barrier();                          // collective: buf(kt) ready
        __builtin_amdgcn_sched_barrier(0);

        const char* buf = lds + ((kt & 1) ? 32768 : 0);

        h16x8 a_h[4], a_l[4];
        #pragma unroll
        for (int m = 0; m < 4; ++m) {
            a_h[m] = *(const h16x8*)(buf + aoffH[m]);
            a_l[m] = *(const h16x8*)(buf + aoffL[m]);
        }
        #pragma unroll
        for (int n = 0; n < 4; ++n) {
            h16x8 b_h = *(const h16x8*)(buf + boffH[n]);
            h16x8 b_l = *(const h16x8*)(buf + boffL[n]);
            #pragma unroll
            for (int m = 0; m < 4; ++m) {
                acc1[m][n] = __builtin_amdgcn_mfma_f32_16x16x32_f16(a_h[m], b_h, acc1[m][n], 0, 0, 0);
                acc2[m][n] = __builtin_amdgcn_mfma_f32_16x16x32_f16(a_h[m], b_l, acc2[m][n], 0, 0, 0);
                acc2[m][n] = __builtin_amdgcn_mfma_f32_16x16x32_f16(a_l[m], b_h, acc2[m][n], 0, 0, 0);
            }
        }

        __builtin_amdgcn_sched_barrier(0);
        __builtin_amdgcn_s_barrier();                          // all waves done reading buf(kt)
        __builtin_amdgcn_sched_barrier(0);

        if (kt + 2 < NT) {
            // S(kt+2) -> buf((kt+2)&1) == buf(kt&1), just released by compute(kt)
            STAGE(kt & 1, kt + 2);
            __builtin_amdgcn_sched_barrier(0);
        }
    }
#undef STAGE

    // ---- epilogue: T .* e2, reduce over this block's 128 e-columns ----
    // C/D layout (m89): col = lane&15, row = (lane>>4)*4 + j
    float rsum[16];
    #pragma unroll
    for (int i = 0; i < 16; ++i) rsum[i] = 0.f;

    #pragma unroll
    for (int m = 0; m < 4; ++m) {
        #pragma unroll
        for (int n = 0; n < 4; ++n) {
            const int col = e0 + wc + n * 16 + lrow;
            #pragma unroll
            for (int j = 0; j < 4; ++j) {
                const int row = b0 + wr + m * 16 + lq * 4 + j;
                float tv = acc1[m][n][j] + acc2[m][n][j] * (1.0f / 2048.0f);
                rsum[m * 4 + j] += tv * e2[(size_t)row * D_SZ + col];
            }
        }
    }

    #pragma unroll
    for (int i = 0; i < 16; ++i) {
        float v = rsum[i];
        v += __shfl_xor(v, 1, 16);
        v += __shfl_xor(v, 2, 16);
        v += __shfl_xor(v, 4, 16);
        v += __shfl_xor(v, 8, 16);
        if (lrow == 0) {
            const int row = b0 + wr + (i >> 2) * 16 + lq * 4 + (i & 3);
            atomicAdd(out + (size_t)k * B_SZ + row, v);
        }
    }
}

// ================= fallback path (round-1 bilinear, used if ws too small) =================
__device__ __forceinline__ int swz_fb(int row, int byte_in_row) {
    int slot = byte_in_row >> 4;
    int in   = byte_in_row & 15;
    return row * 128 + (((slot ^ (row & 7)) << 4) | in);
}
__device__ __forceinline__ void split_fb(float x, unsigned short& h, unsigned short& l) {
    _Float16 hf = (_Float16)x;
    float hff = (float)hf;
    _Float16 lf = (_Float16)((x - hff) * 2048.0f);
    h = __builtin_bit_cast(unsigned short, hf);
    l = __builtin_bit_cast(unsigned short, lf);
}
__global__ __launch_bounds__(256, 2)
void ntl_bilinear_fb(const float* __restrict__ e1, const float* __restrict__ e2,
                     const float* __restrict__ W, float* __restrict__ out) {
    __shared__ __align__(16) char smem[65536];
    char* const Ah = smem;
    char* const Al = smem + 16384;
    char* const Bh = smem + 32768;
    char* const Bl = smem + 49152;
    const int bid = blockIdx.x;
    const int k   = bid >> 8;
    const int rem = bid & 255;
    const int b0  = (rem >> 3) * 128;
    const int e0  = (rem & 7) * 128;
    const int t  = threadIdx.x;
    const int l  = t & 63;
    const int w  = t >> 6;
    const int wr = (w >> 1) * 64;
    const int wc = (w & 1) * 64;
    const int lrow = l & 15;
    const int lq   = l >> 4;
    f32x4 acc1[4][4], acc2[4][4];
    #pragma unroll
    for (int m = 0; m < 4; ++m)
        #pragma unroll
        for (int n = 0; n < 4; ++n) {
            acc1[m][n] = f32x4{0.f, 0.f, 0.f, 0.f};
            acc2[m][n] = f32x4{0.f, 0.f, 0.f, 0.f};
        }
    const int sa_row = t >> 4;
    const int sa_cg  = (t & 15) * 4;
    const int sb_e   = t & 127;
    const int sb_dg  = t >> 7;
    const float* const e1b = e1 + (size_t)b0 * D_SZ;
    const float* const wb  = W + ((size_t)k * D_SZ) * D_SZ + e0 + sb_e;
    for (int kt = 0; kt < 16; ++kt) {
        const int d0 = kt * 64;
        #pragma unroll
        for (int p = 0; p < 8; ++p) {
            const int r = sa_row + p * 16;
            f32x4 vv4 = *(const f32x4*)(e1b + (size_t)r * D_SZ + d0 + sa_cg);
            unsigned short hh[4], ll[4];
            #pragma unroll
            for (int qq = 0; qq < 4; ++qq) split_fb(vv4[qq], hh[qq], ll[qq]);
            u32x2 hv = { (unsigned)hh[0] | ((unsigned)hh[1] << 16),
                         (unsigned)hh[2] | ((unsigned)hh[3] << 16) };
            u32x2 lv = { (unsigned)ll[0] | ((unsigned)ll[1] << 16),
                         (unsigned)ll[2] | ((unsigned)ll[3] << 16) };
            const int ad = swz_fb(r, sa_cg * 2);
            *(u32x2*)(Ah + ad) = hv;
            *(u32x2*)(Al + ad) = lv;
        }
        {
            const float* ws2 = wb + (size_t)(d0 + sb_dg * 32) * D_SZ;
            #pragma unroll
            for (int gg = 0; gg < 4; ++gg) {
                unsigned short hh[8], ll[8];
                #pragma unroll
                for (int i = 0; i < 8; ++i)
                    split_fb(ws2[(size_t)(gg * 8 + i) * D_SZ], hh[i], ll[i]);
                u32x4 hv = { (unsigned)hh[0] | ((unsigned)hh[1] << 16),
                             (unsigned)hh[2] | ((unsigned)hh[3] << 16),
                             (unsigned)hh[4] | ((unsigned)hh[5] << 16),
                             (unsigned)hh[6] | ((unsigned)hh[7] << 16) };
                u32x4 lv = { (unsigned)ll[0] | ((unsigned)ll[1] << 16),
                             (unsigned)ll[2] | ((unsigned)ll[3] << 16),
                             (unsigned)ll[4] | ((unsigned)ll[5] << 16),
                             (unsigned)ll[6] | ((unsigned)ll[7] << 16) };
                const int ad = swz_fb(sb_e, (sb_dg * 32 + gg * 8) * 2);
                *(u32x4*)(Bh + ad) = hv;
                *(u32x4*)(Bl + ad) = lv;
            }
        }
        __syncthreads();
        #pragma unroll
        for (int kk = 0; kk < 2; ++kk) {
            const int kb = kk * 64 + lq * 16;
            h16x8 a_h[4], a_l[4];
            #pragma unroll
            for (int m = 0; m < 4; ++m) {
                const int ad = swz_fb(wr + m * 16 + lrow, kb);
                a_h[m] = *(const h16x8*)(Ah + ad);
                a_l[m] = *(const h16x8*)(Al + ad);
            }
            #pragma unroll
            for (int n = 0; n < 4; ++n) {
                const int bd = swz_fb(wc + n * 16 + lrow, kb);
                h16x8 b_h = *(const h16x8*)(Bh + bd);
                h16x8 b_l = *(const h16x8*)(Bl + bd);
                #pragma unroll
                for (int m = 0; m < 4; ++m) {
                    acc1[m][n] = __builtin_amdgcn_mfma_f32_16x16x32_f16(a_h[m], b_h, acc1[m][n], 0, 0, 0);
                    acc2[m][n] = __builtin_amdgcn_mfma_f32_16x16x32_f16(a_h[m], b_l, acc2[m][n], 0, 0, 0);
                    acc2[m][n] = __builtin_amdgcn_mfma_f32_16x16x32_f16(a_l[m], b_h, acc2[m][n], 0, 0, 0);
                }
            }
        }
        __syncthreads();
    }
    float rsum[16];
    #pragma unroll
    for (int i = 0; i < 16; ++i) rsum[i] = 0.f;
    #pragma unroll
    for (int m = 0; m < 4; ++m) {
        #pragma unroll
        for (int n = 0; n < 4; ++n) {
            const int col = e0 + wc + n * 16 + lrow;
            #pragma unroll
            for (int jq = 0; jq < 4; ++jq) {
                const int row = b0 + wr + m * 16 + lq * 4 + jq;
                float tv = acc1[m][n][jq] + acc2[m][n][jq] * (1.0f / 2048.0f);
                rsum[m * 4 + jq] += tv * e2[(size_t)row * D_SZ + col];
            }
        }
    }
    #pragma unroll
    for (int i = 0; i < 16; ++i) {
        float vv = rsum[i];
        vv += __shfl_xor(vv, 1, 16);
        vv += __shfl_xor(vv, 2, 16);
        vv += __shfl_xor(vv, 4, 16);
        vv += __shfl_xor(vv, 8, 16);
        if (lrow == 0) {
            const int row = b0 + wr + (i >> 2) * 16 + lq * 4 + (i & 3);
            atomicAdd(out + (size_t)k * B_SZ + row, vv);
        }
    }
}

// ---------------- ff / sumb / tanh ----------------
__global__ __launch_bounds__(256)
void ntl_ff(const float* __restrict__ e1, const float* __restrict__ e2,
            const float* __restrict__ V, float* __restrict__ out) {
    __shared__ float vt[32 * 258];
    const int t  = threadIdx.x;
    const int c  = t & 31;
    const int rl = t >> 5;
    const int r  = blockIdx.x * 8 + rl;
    float acc = 0.f;
    for (int j0 = 0; j0 < 2 * D_SZ; j0 += 256) {
        __syncthreads();
        #pragma unroll
        for (int i = 0; i < 32; ++i) {
            const int f = i * 256 + t;
            vt[(f & 31) * 258 + (f >> 5)] = V[(size_t)j0 * K_SZ + f];
        }
        __syncthreads();
        const float* src = (j0 < D_SZ) ? (e1 + (size_t)r * D_SZ + j0)
                                       : (e2 + (size_t)r * D_SZ + (j0 - D_SZ));
        #pragma unroll 8
        for (int jj = 0; jj < 256; jj += 2) {
            f32x2 a  = *(const f32x2*)(src + jj);
            f32x2 vv = *(const f32x2*)(&vt[c * 258 + jj]);
            acc += a[0] * vv[0] + a[1] * vv[1];
        }
    }
    out[(size_t)r * K_SZ + c] += acc;
}

__global__ void ntl_sumb(const float* __restrict__ b, float* __restrict__ ws) {
    __shared__ float red[256];
    const int t = threadIdx.x;
    red[t] = b[t] + b[t + 256] + b[t + 512] + b[t + 768];
    __syncthreads();
    for (int s = 128; s > 0; s >>= 1) {
        if (t < s) red[t] += red[t + s];
        __syncthreads();
    }
    if (t == 0) ws[0] = red[0];
}

__global__ void ntl_tanh(float* __restrict__ out, const float* __restrict__ ws) {
    const int p = blockIdx.x * 256 + threadIdx.x;
    out[p] = tanhf(out[p] + ws[0]);
}

extern "C" void kernel_launch(void* const* d_in, const int* in_sizes, int n_in,
                              void* d_out, int out_size, void* d_ws, size_t ws_size,
                              hipStream_t stream) {
    const float* e1 = (const float*)d_in[0];
    const float* e2 = (const float*)d_in[1];
    const float* W  = (const float*)d_in[2];
    const float* V  = (const float*)d_in[3];
    const float* b  = (const float*)d_in[4];
    float* out = (float*)d_out;

    const size_t WT = (size_t)K_SZ * D_SZ * D_SZ;
    const size_t ET = (size_t)B_SZ * D_SZ;
    const size_t need = (2 * WT + 2 * ET) * sizeof(_Float16) + 16;

    hipMemsetAsync(d_out, 0, (size_t)B_SZ * K_SZ * sizeof(float), stream);

    if (ws_size >= need) {
        _Float16* Wh = (_Float16*)d_ws;
        _Float16* Wl = Wh + WT;
        _Float16* ehp = Wl + WT;
        _Float16* elp = ehp + ET;
        float* sb = (float*)(elp + ET);
        ntl_sumb<<<1, 256, 0, stream>>>(b, sb);
        ntl_prep_w<<<dim3(K_SZ * 256), dim3(256), 0, stream>>>(W, Wh, Wl);
        ntl_prep_e<<<dim3((int)(ET / 1024)), dim3(256), 0, stream>>>(e1, ehp, elp);
        ntl_bilinear7<<<dim3(K_SZ * 256), dim3(256), 0, stream>>>(ehp, elp, Wh, Wl, e2, out);
        ntl_ff<<<dim3(B_SZ / 8), dim3(256), 0, stream>>>(e1, e2, V, out);
        ntl_tanh<<<dim3((B_SZ * K_SZ) / 256), dim3(256), 0, stream>>>(out, sb);
    } else {
        float* sb = (float*)d_ws;
        ntl_sumb<<<1, 256, 0, stream>>>(b, sb);
        ntl_bilinear_fb<<<dim3(K_SZ * 256), dim3(256), 0, stream>>>(e1, e2, W, out);
        ntl_ff<<<dim3(B_SZ / 8), dim3(256), 0, stream>>>(e1, e2, V, out);
        ntl_tanh<<<dim3((B_SZ * K_SZ) / 256), dim3(256), 0, stream>>>(out, sb);
    }
}

// Round 9
// 845.797 us; speedup vs baseline: 1.3182x; 1.0026x over previous
//
#include <hip/hip_runtime.h>

#define B_SZ 4096
#define D_SZ 1024
#define K_SZ 32
#define NT   32          // K-depth steps of 32

typedef _Float16 h16x8 __attribute__((ext_vector_type(8)));
typedef float f32x4 __attribute__((ext_vector_type(4)));
typedef float f32x2 __attribute__((ext_vector_type(2)));
typedef unsigned int u32x2 __attribute__((ext_vector_type(2)));
typedef unsigned int u32x4 __attribute__((ext_vector_type(4)));
typedef unsigned short u16x4 __attribute__((ext_vector_type(4)));

// async global->LDS, 16B per lane (wave-uniform LDS base + lane*16)
#define GLOAD16(gp, sp) __builtin_amdgcn_global_load_lds( \
    (const __attribute__((address_space(1))) void*)(gp),  \
    (__attribute__((address_space(3))) void*)(sp), 16, 0, 0)

// fp32 -> fp16 hi + fp16 lo*2^11 (lo scaled to stay normal)
__device__ __forceinline__ void split1(float x, _Float16& h, _Float16& l) {
    h = (_Float16)x;
    l = (_Float16)((x - (float)h) * 2048.0f);
}

// ---------------- prepass: W[k][d][e] f32 -> Wt_h/Wt_l[k][e][d] fp16 ----------------
__global__ __launch_bounds__(256)
void ntl_prep_w(const float* __restrict__ W,
                _Float16* __restrict__ Wh, _Float16* __restrict__ Wl) {
    __shared__ float tile[64 * 69];
    const int bid = blockIdx.x;
    const int k  = bid >> 8;
    const int d0 = ((bid >> 4) & 15) << 6;
    const int e0 = (bid & 15) << 6;
    const int t  = threadIdx.x;
    const int r  = t >> 4;
    const int c4 = (t & 15) << 2;

    const float* src = W + ((size_t)k * D_SZ + d0) * D_SZ + e0;
    #pragma unroll
    for (int p = 0; p < 4; ++p) {
        f32x4 v = *(const f32x4*)(src + (size_t)(p * 16 + r) * D_SZ + c4);
        float* dst = &tile[(p * 16 + r) * 69 + c4];
        dst[0] = v[0]; dst[1] = v[1]; dst[2] = v[2]; dst[3] = v[3];
    }
    __syncthreads();
    #pragma unroll
    for (int p = 0; p < 4; ++p) {
        const int e = p * 16 + r;
        u16x4 hh, ll;
        #pragma unroll
        for (int q = 0; q < 4; ++q) {
            float v = tile[(c4 + q) * 69 + e];
            _Float16 h, l;
            split1(v, h, l);
            hh[q] = __builtin_bit_cast(unsigned short, h);
            ll[q] = __builtin_bit_cast(unsigned short, l);
        }
        const size_t o = ((size_t)k * D_SZ + e0 + e) * D_SZ + d0 + c4;
        *(u16x4*)(Wh + o) = hh;
        *(u16x4*)(Wl + o) = ll;
    }
}

// ---------------- prepass: e1 f32 -> e1_h/e1_l fp16 ----------------
__global__ __launch_bounds__(256)
void ntl_prep_e(const float* __restrict__ e1,
                _Float16* __restrict__ eh, _Float16* __restrict__ el) {
    const size_t i = ((size_t)blockIdx.x * 256 + threadIdx.x) * 4;
    f32x4 v = *(const f32x4*)(e1 + i);
    u16x4 hh, ll;
    #pragma unroll
    for (int q = 0; q < 4; ++q) {
        _Float16 h, l;
        split1(v[q], h, l);
        hh[q] = __builtin_bit_cast(unsigned short, h);
        ll[q] = __builtin_bit_cast(unsigned short, l);
    }
    *(u16x4*)(eh + i) = hh;
    *(u16x4*)(el + i) = ll;
}

// ---------------- main bilinear: 128x128, BK=32, 4 waves, counted-vmcnt dbuf ----------
// R8 buffer protocol + XCD placement, unchanged. ONE change: the compute section is
// re-shaped into 4 interleaved clusters {issue next B ds_read pair -> 12 MFMA on the
// current pair}, fenced by sched_barrier(0), with setprio(1) around the MFMA cluster.
// Breaks the CU-wide LDS-phase/MFMA-phase convoy (R8: iter ~= LDS 1500cy + MFMA 1862cy
// serialized); with interleave the two pipes overlap across the 8 resident waves.
__global__ __launch_bounds__(256, 2)
void ntl_bilinear8(const _Float16* __restrict__ eh, const _Float16* __restrict__ el,
                   const _Float16* __restrict__ Wh, const _Float16* __restrict__ Wl,
                   const float* __restrict__ e2, float* __restrict__ out) {
    __shared__ __align__(16) char lds[65536];

    const int bid = blockIdx.x;
    const int xcd = bid & 7;           // HW round-robin: bid%8 -> XCD
    const int seq = bid >> 3;          // 0..1023, in-order within an XCD
    const int k   = seq >> 5;          // 32 (slowest: W[k] streams once)
    const int e_t = (seq >> 2) & 7;    // 8 e-tiles
    const int bl  = seq & 3;           // 4 b-tiles per XCD (innermost)
    const int b0  = (xcd * 4 + bl) * 128;
    const int e0  = e_t * 128;

    const int t  = threadIdx.x;
    const int l  = t & 63;
    const int w  = t >> 6;             // 0..3
    const int wr = (w >> 1) * 64;
    const int wc = (w & 1) * 64;
    const int lrow = l & 15;
    const int lq   = l >> 4;           // 0..3

    f32x4 acc1[4][4];   // hi*hi
    f32x4 acc2[4][4];   // hi*lo' + lo'*hi  (scale 2^11)
    #pragma unroll
    for (int m = 0; m < 4; ++m)
        #pragma unroll
        for (int n = 0; n < 4; ++n) {
            acc1[m][n] = f32x4{0.f, 0.f, 0.f, 0.f};
            acc2[m][n] = f32x4{0.f, 0.f, 0.f, 0.f};
        }

    // ---- staging source addressing ----
    const int sline = l >> 3;
    const int sx    = (l & 7) ^ sline;
    const int hl    = sx >> 2;
    const int lqs   = sx & 3;

    const _Float16* aBase = hl ? el : eh;
    const _Float16* bBase = hl ? Wl : Wh;
    const _Float16* gA[4];
    const _Float16* gB[4];
    #pragma unroll
    for (int i = 0; i < 4; ++i) {
        const int row = w * 32 + i * 8 + sline;
        gA[i] = aBase + (size_t)(b0 + row) * D_SZ + lqs * 8;
        gB[i] = bBase + ((size_t)k * D_SZ + e0 + row) * D_SZ + lqs * 8;
    }
    const int sOff = w * 32 * 128;     // byte offset of wave's first line

#define STAGE(bufsel, ktv) do {                                          \
        char* bb = lds + ((bufsel) ? 32768 : 0);                         \
        const size_t kb = (size_t)(ktv) * 32;                            \
        GLOAD16(gA[0] + kb, bb + sOff);                                  \
        GLOAD16(gA[1] + kb, bb + sOff + 1024);                           \
        GLOAD16(gA[2] + kb, bb + sOff + 2048);                           \
        GLOAD16(gA[3] + kb, bb + sOff + 3072);                           \
        GLOAD16(gB[0] + kb, bb + 16384 + sOff);                          \
        GLOAD16(gB[1] + kb, bb + 16384 + sOff + 1024);                   \
        GLOAD16(gB[2] + kb, bb + 16384 + sOff + 2048);                   \
        GLOAD16(gB[3] + kb, bb + 16384 + sOff + 3072);                   \
    } while (0)

    // ---- ds_read offsets (R2-verified conflict-free family) ----
    int aoffH[4], aoffL[4], boffH[4], boffL[4];
    #pragma unroll
    for (int m = 0; m < 4; ++m) {
        const int r = wr + m * 16 + lrow;
        aoffH[m] = r * 128 + ((lq       ^ (r & 7)) << 4);
        aoffL[m] = r * 128 + (((4 | lq) ^ (r & 7)) << 4);
    }
    #pragma unroll
    for (int n = 0; n < 4; ++n) {
        const int r = wc + n * 16 + lrow;
        boffH[n] = 16384 + r * 128 + ((lq       ^ (r & 7)) << 4);
        boffL[n] = 16384 + r * 128 + (((4 | lq) ^ (r & 7)) << 4);
    }

    // MFMA cluster for one B-fragment pair (12 MFMA), setprio-wrapped
#define CLUSTER(nn, BH, BL) do {                                                            \
        __builtin_amdgcn_s_setprio(1);                                                      \
        _Pragma("unroll")                                                                   \
        for (int m = 0; m < 4; ++m) {                                                       \
            acc1[m][nn] = __builtin_amdgcn_mfma_f32_16x16x32_f16(a_h[m], BH, acc1[m][nn], 0, 0, 0); \
            acc2[m][nn] = __builtin_amdgcn_mfma_f32_16x16x32_f16(a_h[m], BL, acc2[m][nn], 0, 0, 0); \
            acc2[m][nn] = __builtin_amdgcn_mfma_f32_16x16x32_f16(a_l[m], BH, acc2[m][nn], 0, 0, 0); \
        }                                                                                   \
        __builtin_amdgcn_s_setprio(0);                                                      \
    } while (0)

    // prologue: stage t=0 -> buf0, t=1 -> buf1  (16 outstanding)
    STAGE(0, 0);
    STAGE(1, 1);

    for (int kt = 0; kt < NT; ++kt) {
        if (kt < NT - 1) {
            asm volatile("s_waitcnt vmcnt(8)" ::: "memory");   // S(kt) landed; S(kt+1) in flight
        } else {
            asm volatile("s_waitcnt vmcnt(0)" ::: "memory");
        }
        __builtin_amdgcn_sched_barrier(0);
        __builtin_amdgcn_s_barrier();                          // collective: buf(kt) ready
        __builtin_amdgcn_sched_barrier(0);

        const char* buf = lds + ((kt & 1) ? 32768 : 0);

        // cluster 0 reads: A fragments + first B pair
        h16x8 a_h[4], a_l[4];
        h16x8 bhA = *(const h16x8*)(buf + boffH[0]);
        h16x8 blA = *(const h16x8*)(buf + boffL[0]);
        #pragma unroll
        for (int m = 0; m < 4; ++m) {
            a_h[m] = *(const h16x8*)(buf + aoffH[m]);
            a_l[m] = *(const h16x8*)(buf + aoffL[m]);
        }
        __builtin_amdgcn_sched_barrier(0);

        // n=0: issue B(1) reads, MFMA on B(0)
        h16x8 bhB = *(const h16x8*)(buf + boffH[1]);
        h16x8 blB = *(const h16x8*)(buf + boffL[1]);
        CLUSTER(0, bhA, blA);
        __builtin_amdgcn_sched_barrier(0);

        // n=1: issue B(2), MFMA on B(1)
        bhA = *(const h16x8*)(buf + boffH[2]);
        blA = *(const h16x8*)(buf + boffL[2]);
        CLUSTER(1, bhB, blB);
        __builtin_amdgcn_sched_barrier(0);

        // n=2: issue B(3), MFMA on B(2)
        bhB = *(const h16x8*)(buf + boffH[3]);
        blB = *(const h16x8*)(buf + boffL[3]);
        CLUSTER(2, bhA, blA);
        __builtin_amdgcn_sched_barrier(0);

        // n=3: MFMA on B(3)
        CLUSTER(3, bhB, blB);

        __builtin_amdgcn_sched_barrier(0);
        __builtin_amdgcn_s_barrier();                          // all waves done reading buf(kt)
        __builtin_amdgcn_sched_barrier(0);

        if (kt + 2 < NT) {
            // S(kt+2) -> buf((kt+2)&1) == buf(kt&1), just released by compute(kt)
            STAGE(kt & 1, kt + 2);
            __builtin_amdgcn_sched_barrier(0);
        }
    }
#undef CLUSTER
#undef STAGE

    // ---- epilogue: T .* e2, reduce over this block's 128 e-columns ----
    // C/D layout (m89): col = lane&15, row = (lane>>4)*4 + j
    float rsum[16];
    #pragma unroll
    for (int i = 0; i < 16; ++i) rsum[i] = 0.f;

    #pragma unroll
    for (int m = 0; m < 4; ++m) {
        #pragma unroll
        for (int n = 0; n < 4; ++n) {
            const int col = e0 + wc + n * 16 + lrow;
            #pragma unroll
            for (int j = 0; j < 4; ++j) {
                const int row = b0 + wr + m * 16 + lq * 4 + j;
                float tv = acc1[m][n][j] + acc2[m][n][j] * (1.0f / 2048.0f);
                rsum[m * 4 + j] += tv * e2[(size_t)row * D_SZ + col];
            }
        }
    }

    #pragma unroll
    for (int i = 0; i < 16; ++i) {
        float v = rsum[i];
        v += __shfl_xor(v, 1, 16);
        v += __shfl_xor(v, 2, 16);
        v += __shfl_xor(v, 4, 16);
        v += __shfl_xor(v, 8, 16);
        if (lrow == 0) {
            const int row = b0 + wr + (i >> 2) * 16 + lq * 4 + (i & 3);
            atomicAdd(out + (size_t)k * B_SZ + row, v);
        }
    }
}

// ================= fallback path (round-1 bilinear, used if ws too small) =================
__device__ __forceinline__ int swz_fb(int row, int byte_in_row) {
    int slot = byte_in_row >> 4;
    int in   = byte_in_row & 15;
    return row * 128 + (((slot ^ (row & 7)) << 4) | in);
}
__device__ __forceinline__ void split_fb(float x, unsigned short& h, unsigned short& l) {
    _Float16 hf = (_Float16)x;
    float hff = (float)hf;
    _Float16 lf = (_Float16)((x - hff) * 2048.0f);
    h = __builtin_bit_cast(unsigned short, hf);
    l = __builtin_bit_cast(unsigned short, lf);
}
__global__ __launch_bounds__(256, 2)
void ntl_bilinear_fb(const float* __restrict__ e1, const float* __restrict__ e2,
                     const float* __restrict__ W, float* __restrict__ out) {
    __shared__ __align__(16) char smem[65536];
    char* const Ah = smem;
    char* const Al = smem + 16384;
    char* const Bh = smem + 32768;
    char* const Bl = smem + 49152;
    const int bid = blockIdx.x;
    const int k   = bid >> 8;
    const int rem = bid & 255;
    const int b0  = (rem >> 3) * 128;
    const int e0  = (rem & 7) * 128;
    const int t  = threadIdx.x;
    const int l  = t & 63;
    const int w  = t >> 6;
    const int wr = (w >> 1) * 64;
    const int wc = (w & 1) * 64;
    const int lrow = l & 15;
    const int lq   = l >> 4;
    f32x4 acc1[4][4], acc2[4][4];
    #pragma unroll
    for (int m = 0; m < 4; ++m)
        #pragma unroll
        for (int n = 0; n < 4; ++n) {
            acc1[m][n] = f32x4{0.f, 0.f, 0.f, 0.f};
            acc2[m][n] = f32x4{0.f, 0.f, 0.f, 0.f};
        }
    const int sa_row = t >> 4;
    const int sa_cg  = (t & 15) * 4;
    const int sb_e   = t & 127;
    const int sb_dg  = t >> 7;
    const float* const e1b = e1 + (size_t)b0 * D_SZ;
    const float* const wb  = W + ((size_t)k * D_SZ) * D_SZ + e0 + sb_e;
    for (int kt = 0; kt < 16; ++kt) {
        const int d0 = kt * 64;
        #pragma unroll
        for (int p = 0; p < 8; ++p) {
            const int r = sa_row + p * 16;
            f32x4 vv4 = *(const f32x4*)(e1b + (size_t)r * D_SZ + d0 + sa_cg);
            unsigned short hh[4], ll[4];
            #pragma unroll
            for (int qq = 0; qq < 4; ++qq) split_fb(vv4[qq], hh[qq], ll[qq]);
            u32x2 hv = { (unsigned)hh[0] | ((unsigned)hh[1] << 16),
                         (unsigned)hh[2] | ((unsigned)hh[3] << 16) };
            u32x2 lv = { (unsigned)ll[0] | ((unsigned)ll[1] << 16),
                         (unsigned)ll[2] | ((unsigned)ll[3] << 16) };
            const int ad = swz_fb(r, sa_cg * 2);
            *(u32x2*)(Ah + ad) = hv;
            *(u32x2*)(Al + ad) = lv;
        }
        {
            const float* ws2 = wb + (size_t)(d0 + sb_dg * 32) * D_SZ;
            #pragma unroll
            for (int gg = 0; gg < 4; ++gg) {
                unsigned short hh[8], ll[8];
                #pragma unroll
                for (int i = 0; i < 8; ++i)
                    split_fb(ws2[(size_t)(gg * 8 + i) * D_SZ], hh[i], ll[i]);
                u32x4 hv = { (unsigned)hh[0] | ((unsigned)hh[1] << 16),
                             (unsigned)hh[2] | ((unsigned)hh[3] << 16),
                             (unsigned)hh[4] | ((unsigned)hh[5] << 16),
                             (unsigned)hh[6] | ((unsigned)hh[7] << 16) };
                u32x4 lv = { (unsigned)ll[0] | ((unsigned)ll[1] << 16),
                             (unsigned)ll[2] | ((unsigned)ll[3] << 16),
                             (unsigned)ll[4] | ((unsigned)ll[5] << 16),
                             (unsigned)ll[6] | ((unsigned)ll[7] << 16) };
                const int ad = swz_fb(sb_e, (sb_dg * 32 + gg * 8) * 2);
                *(u32x4*)(Bh + ad) = hv;
                *(u32x4*)(Bl + ad) = lv;
            }
        }
        __syncthreads();
        #pragma unroll
        for (int kk = 0; kk < 2; ++kk) {
            const int kb = kk * 64 + lq * 16;
            h16x8 a_h[4], a_l[4];
            #pragma unroll
            for (int m = 0; m < 4; ++m) {
                const int ad = swz_fb(wr + m * 16 + lrow, kb);
                a_h[m] = *(const h16x8*)(Ah + ad);
                a_l[m] = *(const h16x8*)(Al + ad);
            }
            #pragma unroll
            for (int n = 0; n < 4; ++n) {
                const int bd = swz_fb(wc + n * 16 + lrow, kb);
                h16x8 b_h = *(const h16x8*)(Bh + bd);
                h16x8 b_l = *(const h16x8*)(Bl + bd);
                #pragma unroll
                for (int m = 0; m < 4; ++m) {
                    acc1[m][n] = __builtin_amdgcn_mfma_f32_16x16x32_f16(a_h[m], b_h, acc1[m][n], 0, 0, 0);
                    acc2[m][n] = __builtin_amdgcn_mfma_f32_16x16x32_f16(a_h[m], b_l, acc2[m][n], 0, 0, 0);
                    acc2[m][n] = __builtin_amdgcn_mfma_f32_16x16x32_f16(a_l[m], b_h, acc2[m][n], 0, 0, 0);
                }
            }
        }
        __syncthreads();
    }
    float rsum[16];
    #pragma unroll
    for (int i = 0; i < 16; ++i) rsum[i] = 0.f;
    #pragma unroll
    for (int m = 0; m < 4; ++m) {
        #pragma unroll
        for (int n = 0; n < 4; ++n) {
            const int col = e0 + wc + n * 16 + lrow;
            #pragma unroll
            for (int jq = 0; jq < 4; ++jq) {
                const int row = b0 + wr + m * 16 + lq * 4 + jq;
                float tv = acc1[m][n][jq] + acc2[m][n][jq] * (1.0f / 2048.0f);
                rsum[m * 4 + jq] += tv * e2[(size_t)row * D_SZ + col];
            }
        }
    }
    #pragma unroll
    for (int i = 0; i < 16; ++i) {
        float vv = rsum[i];
        vv += __shfl_xor(vv, 1, 16);
        vv += __shfl_xor(vv, 2, 16);
        vv += __shfl_xor(vv, 4, 16);
        vv += __shfl_xor(vv, 8, 16);
        if (lrow == 0) {
            const int row = b0 + wr + (i >> 2) * 16 + lq * 4 + (i & 3);
            atomicAdd(out + (size_t)k * B_SZ + row, vv);
        }
    }
}

// ---------------- ff / sumb / tanh ----------------
__global__ __launch_bounds__(256)
void ntl_ff(const float* __restrict__ e1, const float* __restrict__ e2,
            const float* __restrict__ V, float* __restrict__ out) {
    __shared__ float vt[32 * 258];
    const int t  = threadIdx.x;
    const int c  = t & 31;
    const int rl = t >> 5;
    const int r  = blockIdx.x * 8 + rl;
    float acc = 0.f;
    for (int j0 = 0; j0 < 2 * D_SZ; j0 += 256) {
        __syncthreads();
        #pragma unroll
        for (int i = 0; i < 32; ++i) {
            const int f = i * 256 + t;
            vt[(f & 31) * 258 + (f >> 5)] = V[(size_t)j0 * K_SZ + f];
        }
        __syncthreads();
        const float* src = (j0 < D_SZ) ? (e1 + (size_t)r * D_SZ + j0)
                                       : (e2 + (size_t)r * D_SZ + (j0 - D_SZ));
        #pragma unroll 8
        for (int jj = 0; jj < 256; jj += 2) {
            f32x2 a  = *(const f32x2*)(src + jj);
            f32x2 vv = *(const f32x2*)(&vt[c * 258 + jj]);
            acc += a[0] * vv[0] + a[1] * vv[1];
        }
    }
    out[(size_t)r * K_SZ + c] += acc;
}

__global__ void ntl_sumb(const float* __restrict__ b, float* __restrict__ ws) {
    __shared__ float red[256];
    const int t = threadIdx.x;
    red[t] = b[t] + b[t + 256] + b[t + 512] + b[t + 768];
    __syncthreads();
    for (int s = 128; s > 0; s >>= 1) {
        if (t < s) red[t] += red[t + s];
        __syncthreads();
    }
    if (t == 0) ws[0] = red[0];
}

__global__ void ntl_tanh(float* __restrict__ out, const float* __restrict__ ws) {
    const int p = blockIdx.x * 256 + threadIdx.x;
    out[p] = tanhf(out[p] + ws[0]);
}

extern "C" void kernel_launch(void* const* d_in, const int* in_sizes, int n_in,
                              void* d_out, int out_size, void* d_ws, size_t ws_size,
                              hipStream_t stream) {
    const float* e1 = (const float*)d_in[0];
    const float* e2 = (const float*)d_in[1];
    const float* W  = (const float*)d_in[2];
    const float* V  = (const float*)d_in[3];
    const float* b  = (const float*)d_in[4];
    float* out = (float*)d_out;

    const size_t WT = (size_t)K_SZ * D_SZ * D_SZ;
    const size_t ET = (size_t)B_SZ * D_SZ;
    const size_t need = (2 * WT + 2 * ET) * sizeof(_Float16) + 16;

    hipMemsetAsync(d_out, 0, (size_t)B_SZ * K_SZ * sizeof(float), stream);

    if (ws_size >= need) {
        _Float16* Wh = (_Float16*)d_ws;
        _Float16* Wl = Wh + WT;
        _Float16* ehp = Wl + WT;
        _Float16* elp = ehp + ET;
        float* sb = (float*)(elp + ET);
        ntl_sumb<<<1, 256, 0, stream>>>(b, sb);
        ntl_prep_w<<<dim3(K_SZ * 256), dim3(256), 0, stream>>>(W, Wh, Wl);
        ntl_prep_e<<<dim3((int)(ET / 1024)), dim3(256), 0, stream>>>(e1, ehp, elp);
        ntl_bilinear8<<<dim3(K_SZ * 256), dim3(256), 0, stream>>>(ehp, elp, Wh, Wl, e2, out);
        ntl_ff<<<dim3(B_SZ / 8), dim3(256), 0, stream>>>(e1, e2, V, out);
        ntl_tanh<<<dim3((B_SZ * K_SZ) / 256), dim3(256), 0, stream>>>(out, sb);
    } else {
        float* sb = (float*)d_ws;
        ntl_sumb<<<1, 256, 0, stream>>>(b, sb);
        ntl_bilinear_fb<<<dim3(K_SZ * 256), dim3(256), 0, stream>>>(e1, e2, W, out);
        ntl_ff<<<dim3(B_SZ / 8), dim3(256), 0, stream>>>(e1, e2, V, out);
        ntl_tanh<<<dim3((B_SZ * K_SZ) / 256), dim3(256), 0, stream>>>(out, sb);
    }
}